// Round 1
// baseline (503.648 us; speedup 1.0000x reference)
//
#include <hip/hip_runtime.h>

#define NV 8192

__global__ void cooc_copy_kernel(const float4* __restrict__ w,
                                 float4* __restrict__ out, int n4) {
    int idx = blockIdx.x * blockDim.x + threadIdx.x;
    int stride = gridDim.x * blockDim.x;
    for (int i = idx; i < n4; i += stride) {
        out[i] = w[i];
    }
}

__global__ void cooc_scatter_kernel(const int* __restrict__ left,
                                    const int* __restrict__ right,
                                    float* __restrict__ out, int n) {
    int idx = blockIdx.x * blockDim.x + threadIdx.x;
    int stride = gridDim.x * blockDim.x;
    for (int i = idx; i < n; i += stride) {
        int l = left[i];
        int r = right[i];
        atomicAdd(&out[(size_t)l * NV + r], 1.0f);
    }
}

extern "C" void kernel_launch(void* const* d_in, const int* in_sizes, int n_in,
                              void* d_out, int out_size, void* d_ws, size_t ws_size,
                              hipStream_t stream) {
    const int* left  = (const int*)d_in[0];
    const int* right = (const int*)d_in[1];
    const float* w   = (const float*)d_in[2];
    float* out = (float*)d_out;

    // 1) out = weight  (vectorized copy; out_size = 8192*8192, divisible by 4)
    int n4 = out_size / 4;
    cooc_copy_kernel<<<2048, 256, 0, stream>>>(
        (const float4*)w, (float4*)out, n4);

    // 2) out[l, r] += 1.0 for each pair (duplicates accumulate via atomics)
    int n = in_sizes[0];
    cooc_scatter_kernel<<<2048, 256, 0, stream>>>(left, right, out, n);
}